// Round 4
// baseline (5466.736 us; speedup 1.0000x reference)
//
#include <hip/hip_runtime.h>

// Problem constants (fixed by the reference): B=64, T=512, D=1024, R=1024, O=1024
#define BB 64
#define TT 512
#define DD 1024
#define RR 1024

#define SCAN_BLOCKS 32
#define RED_STRIDE 68                         // f32 elems; 64 + 4 pad
#define SCAN_LDS_BYTES (4 * 64 * RED_STRIDE * 4)   // 69632: K-reduce only

typedef __bf16 bf16x8 __attribute__((ext_vector_type(8)));
typedef float f32x4 __attribute__((ext_vector_type(4)));
typedef unsigned short us4 __attribute__((ext_vector_type(4)));
typedef unsigned int u32x4 __attribute__((ext_vector_type(4)));
typedef unsigned int u32x2 __attribute__((ext_vector_type(2)));
typedef unsigned long long u64;

__device__ inline unsigned short f2bf(float f) {
  unsigned int u = __float_as_uint(f);
  u = (u + 0x7fffu + ((u >> 16) & 1u)) >> 16;   // RNE
  return (unsigned short)u;
}
__device__ inline float bf2f(unsigned short b) {
  return __uint_as_float(((unsigned int)b) << 16);
}

// Coherent 16B load (sc0 sc1): served by the coherence point -- the validated
// path for reading other blocks' published h. Caller must waitcnt via asm.
__device__ inline u32x4 ld16_sc(const void* p) {
  u32x4 r;
  asm volatile("global_load_dwordx4 %0, %1, off sc0 sc1"
               : "=v"(r) : "v"(p) : "memory");
  return r;
}
// plain cached 8B load (read-only xhz stream), asm so it's vmcnt-counted
// at a known position in the pipeline.
__device__ inline u32x2 ld8_g(const void* p) {
  u32x2 r;
  asm volatile("global_load_dwordx2 %0, %1, off" : "=v"(r) : "v"(p) : "memory");
  return r;
}

// ---- fp32 -> bf16 vectorized convert (n4 = n/4 groups) ----
__global__ void k_f2b4(const float* __restrict__ in, unsigned short* __restrict__ out, int n4) {
  int i = blockIdx.x * blockDim.x + threadIdx.x;
  if (i < n4) {
    const float4 v = ((const float4*)in)[i];
    us4 o;
    o.x = f2bf(v.x); o.y = f2bf(v.y); o.z = f2bf(v.z); o.w = f2bf(v.w);
    ((us4*)out)[i] = o;
  }
}

// ---- transpose 1024x1024 fp32 -> bf16 (out[j][k] = in[k][j]) ----
__global__ __launch_bounds__(256) void k_transpose_bf16(
    const float* __restrict__ in, unsigned short* __restrict__ out) {
  __shared__ float tile[32][33];
  const int bx = blockIdx.x * 32, by0 = blockIdx.y * 32;
  const int tx = threadIdx.x, ty = threadIdx.y;  // block (32,8)
#pragma unroll
  for (int r = 0; r < 32; r += 8)
    tile[ty + r][tx] = in[(size_t)(by0 + ty + r) * 1024 + bx + tx];
  __syncthreads();
#pragma unroll
  for (int r = 0; r < 32; r += 8)
    out[(size_t)(bx + ty + r) * 1024 + by0 + tx] = f2bf(tile[tx][ty + r]);
}

// ---- async global->LDS, 16B per lane ----
__device__ inline void gload_lds16(const unsigned short* g, unsigned short* l) {
  __builtin_amdgcn_global_load_lds(
      (const __attribute__((address_space(1))) unsigned int*)g,
      (__attribute__((address_space(3))) unsigned int*)l, 16, 0, 0);
}

// ---- bf16 GEMM, C[m,n] = sum_k A[m,k]*B[n,k], 128x128 tile, BK=32 ----
// EPI==0: out = xhz time-major [T][B][2048] bf16, bias folded (bh n<1024, bz else)
// EPI==1: out[m*1024+n] bf16 (Mz into Wrec rows 1024..2047)
template <int EPI>
__global__ __launch_bounds__(256) void gemm_bt(
    const unsigned short* __restrict__ A,
    const unsigned short* __restrict__ Bm,
    const float* __restrict__ bias_h,
    const float* __restrict__ bias_z,
    unsigned short* __restrict__ outb, int K) {
  __shared__ __attribute__((aligned(16))) unsigned short As[128 * 32];
  __shared__ __attribute__((aligned(16))) unsigned short Bs[128 * 32];
  const int tid = threadIdx.x;
  const int m0 = blockIdx.y * 128, n0 = blockIdx.x * 128;
  const int lane = tid & 63, wid = tid >> 6;
  const int l16 = lane & 15, quad = lane >> 4;
  const int wm = (wid & 1) * 64, wn = (wid >> 1) * 64;

  f32x4 acc[4][4] = {};

  const int c0 = tid, c1 = 256 + tid;
  const int rowA0 = c0 >> 2, colA0 = (c0 & 3) << 3;
  const int rowA1 = c1 >> 2, colA1 = (c1 & 3) << 3;

  for (int kk = 0; kk < K; kk += 32) {
    __syncthreads();
    gload_lds16(A + (size_t)(m0 + rowA0) * K + kk + colA0, As + c0 * 8);
    gload_lds16(A + (size_t)(m0 + rowA1) * K + kk + colA1, As + c1 * 8);
    gload_lds16(Bm + (size_t)(n0 + rowA0) * K + kk + colA0, Bs + c0 * 8);
    gload_lds16(Bm + (size_t)(n0 + rowA1) * K + kk + colA1, Bs + c1 * 8);
    __syncthreads();
    bf16x8 af[4], bfr[4];
#pragma unroll
    for (int i = 0; i < 4; ++i) {
      af[i] = *(const bf16x8*)&As[(wm + i * 16 + l16) * 32 + quad * 8];
      bfr[i] = *(const bf16x8*)&Bs[(wn + i * 16 + l16) * 32 + quad * 8];
    }
#pragma unroll
    for (int i = 0; i < 4; ++i)
#pragma unroll
      for (int j = 0; j < 4; ++j)
        acc[i][j] = __builtin_amdgcn_mfma_f32_16x16x32_bf16(af[i], bfr[j], acc[i][j], 0, 0, 0);
  }

#pragma unroll
  for (int i = 0; i < 4; ++i) {
#pragma unroll
    for (int j = 0; j < 4; ++j) {
#pragma unroll
      for (int r = 0; r < 4; ++r) {
        const int m = m0 + wm + i * 16 + quad * 4 + r;
        const int n = n0 + wn + j * 16 + l16;
        float v = acc[i][j][r];
        if (EPI == 0) {
          v += (n < 1024) ? bias_h[n] : bias_z[n - 1024];
          const int b = m >> 9;          // m = b*T + t, T=512
          const int t = m & 511;
          outb[((size_t)(t * 64 + b) << 11) + n] = f2bf(v);
        } else {
          outb[(size_t)m * 1024 + n] = f2bf(v);
        }
      }
    }
  }
}

// ---- persistent scan over T=512 steps + output GEMM ----
// 32 blocks x 512 threads (8 waves). Block g owns h-cols [32g, 32g+32); its 64
// MFMA n-cols = 32 Whh rows + 32 Mz rows (B-frags register-resident). Wave
// layout (ks = wid>>1, ng = wid&1): ALL 4 m-tiles (M=64), 2 n-tiles, K-slice
// ks*256. A-fragments are loaded DIRECTLY global->VGPR from the published h
// buffer (sc0 sc1, same coherence path the old LDS staging used) in a depth-2
// counted-vmcnt pipeline -- no LDS h staging, no 4x-redundant LDS A reads.
// LDS holds only the [4][64][68] f32 K-reduce. 3 barriers/step (was 5).
// Flag barrier protocol is kept verbatim from the round-0-validated kernel
// (publish via relaxed AGENT atomics, __syncthreads drains vmcnt, flag store,
// 64-lane poll over 32 flags, __syncthreads).
__global__ __launch_bounds__(512, 2) void scan_out_k(
    const unsigned short* __restrict__ xhz,   // [T][B][2048] bf16
    const unsigned short* __restrict__ Wrec,  // [2048][1024] bf16 (Whh ; Mz)
    const unsigned short* __restrict__ Wyb,   // [1024][1024] bf16
    const float* __restrict__ by,
    unsigned short* __restrict__ hb0, unsigned short* __restrict__ hb1,
    unsigned int* __restrict__ flags,
    float* __restrict__ out) {
  extern __shared__ float red[];   // [4][64][RED_STRIDE]

  const int tid = threadIdx.x, g = blockIdx.x;
  const int lane = tid & 63, wid = tid >> 6;     // 8 waves
  const int l16 = lane & 15, quad = lane >> 4;
  const int ks = wid >> 1, ng = wid & 1;
  const int kw = ks * 256;                       // wave's K slice (bf16 elems)
  const int i0 = g * 32;

  // loop-invariant B fragments: 2 n-tiles x 8 k-chunks -> 64 VGPRs
  bf16x8 bfr[2][8];
#pragma unroll
  for (int j = 0; j < 2; ++j) {
    const int nt = ng * 2 + j;                   // n-tiles {0,1}=Whh, {2,3}=Mz
    const int bcol = (nt < 2) ? (i0 + nt * 16 + l16)
                              : (1024 + i0 + (nt - 2) * 16 + l16);
    const unsigned short* Bb = Wrec + (size_t)bcol * 1024 + kw + quad * 8;
#pragma unroll
    for (int s = 0; s < 8; ++s) bfr[j][s] = *(const bf16x8*)(Bb + s * 32);
  }

  // A-fragment base: row (mt*16 + l16), elems kw + s*32 + quad*8
  const size_t abase = (size_t)l16 * 2048 + (size_t)(kw + quad * 8) * 2;  // bytes

  // elementwise coords: thread owns (b=eb, cols i0+ej .. i0+ej+3)
  const int eb = tid >> 3, ej = (tid & 7) * 4;
  float hold[4] = {0.f, 0.f, 0.f, 0.f};   // fp32 master h, register-resident

  for (int tt = 0; tt < TT; ++tt) {
    const char* hbc = (tt & 1) ? (const char*)hb1 : (const char*)hb0;
    unsigned short* hbn = (tt & 1) ? hb0 : hb1;

    // ---- full-K MFMA, A direct from coherence point, depth-2 pipeline ----
    f32x4 acc[4][2] = {};
    u32x4 tA[3][4];
    u32x2 xh2 = {}, xz2 = {};
#pragma unroll
    for (int mt = 0; mt < 4; ++mt)
      tA[0][mt] = ld16_sc(hbc + abase + mt * 32768);
#pragma unroll
    for (int mt = 0; mt < 4; ++mt)
      tA[1][mt] = ld16_sc(hbc + abase + mt * 32768 + 64);
#pragma unroll
    for (int s = 0; s < 8; ++s) {
      if (s < 6) {
#pragma unroll
        for (int mt = 0; mt < 4; ++mt)
          tA[(s + 2) % 3][mt] = ld16_sc(hbc + abase + mt * 32768 + (s + 2) * 64);
      }
      if (s == 6) {    // xhz issued last; retired after all A chunks
        const char* xp = (const char*)xhz +
            (((((size_t)tt * 64 + eb)) << 11) + i0 + ej) * 2;
        xh2 = ld8_g(xp);
        xz2 = ld8_g(xp + 2048);
      }
      // chunk s is older than >=8/4/0 later A-ops -> counted waits retire it
      if (s < 6)       asm volatile("s_waitcnt vmcnt(8)" ::: "memory");
      else if (s == 6) asm volatile("s_waitcnt vmcnt(6)" ::: "memory");
      else             asm volatile("s_waitcnt vmcnt(2)" ::: "memory");
      __builtin_amdgcn_sched_barrier(0);
#pragma unroll
      for (int mt = 0; mt < 4; ++mt) {
        const bf16x8 a = __builtin_bit_cast(bf16x8, tA[s % 3][mt]);
        acc[mt][0] = __builtin_amdgcn_mfma_f32_16x16x32_bf16(a, bfr[0][s], acc[mt][0], 0, 0, 0);
        acc[mt][1] = __builtin_amdgcn_mfma_f32_16x16x32_bf16(a, bfr[1][s], acc[mt][1], 0, 0, 0);
      }
    }

    // ---- K-reduction partials into LDS ----
#pragma unroll
    for (int mt = 0; mt < 4; ++mt)
#pragma unroll
      for (int j = 0; j < 2; ++j)
#pragma unroll
        for (int r = 0; r < 4; ++r)
          red[(size_t)(ks * 64 + mt * 16 + quad * 4 + r) * RED_STRIDE +
              (ng * 2 + j) * 16 + l16] = acc[mt][j][r];
    __syncthreads();

    // ---- elementwise update (512 threads x 4 elems) ----
    asm volatile("s_waitcnt vmcnt(0)" ::: "memory");   // xh2/xz2 ready
    __builtin_amdgcn_sched_barrier(0);
    float ph[4] = {}, pz[4] = {};
#pragma unroll
    for (int w = 0; w < 4; ++w) {
      const float* rb = red + (size_t)(w * 64 + eb) * RED_STRIDE;
#pragma unroll
      for (int r = 0; r < 4; ++r) {
        ph[r] += rb[ej + r];
        pz[r] += rb[32 + ej + r];
      }
    }
    unsigned short hp[4];
#pragma unroll
    for (int r = 0; r < 4; ++r) {
      const unsigned int xw = xh2[r >> 1], zw = xz2[r >> 1];
      const float xhf = bf2f((unsigned short)((r & 1) ? (xw >> 16) : (xw & 0xffff)));
      const float xzf = bf2f((unsigned short)((r & 1) ? (zw >> 16) : (zw & 0xffff)));
      const float z = 1.0f / (1.0f + __expf(-(xzf + pz[r])));
      const float hbv = fmaxf(xhf + ph[r], 0.0f);
      hold[r] = z * hold[r] + (1.0f - z) * hbv;
      hp[r] = f2bf(hold[r]);
    }
    const u64 pk = (u64)hp[0] | ((u64)hp[1] << 16) | ((u64)hp[2] << 32) | ((u64)hp[3] << 48);
    __hip_atomic_store((u64*)(hbn + (size_t)eb * 1024 + i0 + ej), pk,
                       __ATOMIC_RELAXED, __HIP_MEMORY_SCOPE_AGENT);

    // ---- fence-free flag barrier (round-0 validated) ----
    __syncthreads();   // drains each wave's vmcnt -> all h' stores visible
    if (tid == 0)
      __hip_atomic_store(&flags[g], (unsigned int)(tt + 1),
                         __ATOMIC_RELAXED, __HIP_MEMORY_SCOPE_AGENT);
    if (tid < 64) {
      const unsigned int tgt = (unsigned int)(tt + 1);
      unsigned int v;
      do {
        v = __hip_atomic_load(&flags[tid & 31], __ATOMIC_RELAXED, __HIP_MEMORY_SCOPE_AGENT);
      } while (__any(v < tgt));
    }
    __syncthreads();
  }

  // ---- epilogue: out = h_final @ Wy^T + by ----
  // h_final in hb0 (tt=511 odd writes hb0). Wave (ks, ng): 4 m-tiles x 1 out
  // n-tile (ng). B preloaded to regs (plain loads, older than all asm loads
  // -> counted waits stay conservative-safe).
  {
    const int ocol = i0 + ng * 16 + l16;
    const unsigned short* Byb = Wyb + (size_t)ocol * 1024 + kw + quad * 8;
    bf16x8 byf[8];
#pragma unroll
    for (int s = 0; s < 8; ++s) byf[s] = *(const bf16x8*)(Byb + s * 32);

    f32x4 acc[4] = {};
    u32x4 tA[3][4];
#pragma unroll
    for (int mt = 0; mt < 4; ++mt)
      tA[0][mt] = ld16_sc((const char*)hb0 + abase + mt * 32768);
#pragma unroll
    for (int mt = 0; mt < 4; ++mt)
      tA[1][mt] = ld16_sc((const char*)hb0 + abase + mt * 32768 + 64);
#pragma unroll
    for (int s = 0; s < 8; ++s) {
      if (s < 6) {
#pragma unroll
        for (int mt = 0; mt < 4; ++mt)
          tA[(s + 2) % 3][mt] = ld16_sc((const char*)hb0 + abase + mt * 32768 + (s + 2) * 64);
      }
      if (s < 6)       asm volatile("s_waitcnt vmcnt(8)" ::: "memory");
      else if (s == 6) asm volatile("s_waitcnt vmcnt(4)" ::: "memory");
      else             asm volatile("s_waitcnt vmcnt(0)" ::: "memory");
      __builtin_amdgcn_sched_barrier(0);
#pragma unroll
      for (int mt = 0; mt < 4; ++mt) {
        const bf16x8 a = __builtin_bit_cast(bf16x8, tA[s % 3][mt]);
        acc[mt] = __builtin_amdgcn_mfma_f32_16x16x32_bf16(a, byf[s], acc[mt], 0, 0, 0);
      }
    }
#pragma unroll
    for (int mt = 0; mt < 4; ++mt)
#pragma unroll
      for (int r = 0; r < 4; ++r)
        red[(size_t)(ks * 64 + mt * 16 + quad * 4 + r) * RED_STRIDE +
            ng * 16 + l16] = acc[mt][r];
  }
  __syncthreads();
  {
    float o[4];
#pragma unroll
    for (int r = 0; r < 4; ++r) o[r] = by[i0 + ej + r];
#pragma unroll
    for (int w = 0; w < 4; ++w) {
      const float* rb = red + (size_t)(w * 64 + eb) * RED_STRIDE;
#pragma unroll
      for (int r = 0; r < 4; ++r) o[r] += rb[ej + r];
    }
    float4 ov; ov.x = o[0]; ov.y = o[1]; ov.z = o[2]; ov.w = o[3];
    *(float4*)(out + (size_t)eb * 1024 + i0 + ej) = ov;
  }
}

extern "C" void kernel_launch(void* const* d_in, const int* in_sizes, int n_in,
                              void* d_out, int out_size, void* d_ws, size_t ws_size,
                              hipStream_t stream) {
  const float* x = (const float*)d_in[0];
  const float* Wxh = (const float*)d_in[1];
  const float* bh = (const float*)d_in[2];
  const float* Whh = (const float*)d_in[3];
  const float* Wxz = (const float*)d_in[4];
  const float* bz = (const float*)d_in[5];
  const float* Whz = (const float*)d_in[6];
  const float* Wy = (const float*)d_in[7];
  const float* by = (const float*)d_in[8];
  float* out = (float*)d_out;

  char* ws = (char*)d_ws;
  size_t off = 0;
  auto alloc = [&](size_t bytes) -> void* {
    void* p = ws + off;
    off += (bytes + 255) & ~(size_t)255;
    return p;
  };
  const size_t nX = (size_t)BB * TT * DD;  // 33554432
  unsigned short* xb = (unsigned short*)alloc(nX * 2);                  // x bf16
  unsigned short* Wcat = (unsigned short*)alloc((size_t)2048 * 1024 * 2);  // [Wxh;Wxz]
  unsigned short* WhzT = (unsigned short*)alloc((size_t)1024 * 1024 * 2);  // Whz^T
  unsigned short* Wrec = (unsigned short*)alloc((size_t)2048 * 1024 * 2);  // [Whh;Mz]
  unsigned short* Wyb = (unsigned short*)alloc((size_t)1024 * 1024 * 2);   // Wy bf16
  unsigned short* xhz = (unsigned short*)alloc((size_t)TT * BB * 2048 * 2);  // 128 MB
  unsigned short* hb0 = (unsigned short*)alloc((size_t)BB * RR * 2);
  unsigned short* hb1 = (unsigned short*)alloc((size_t)BB * RR * 2);
  unsigned int* flags = (unsigned int*)alloc(1024);

  hipMemsetAsync(hb0, 0, (size_t)BB * RR * 2, stream);
  hipMemsetAsync(flags, 0, 1024, stream);

  // weight / input conversions
  k_f2b4<<<dim3((unsigned)(nX / 4 / 256)), 256, 0, stream>>>(x, xb, (int)(nX / 4));
  k_f2b4<<<dim3(1024), 256, 0, stream>>>(Wxh, Wcat, 262144);
  k_f2b4<<<dim3(1024), 256, 0, stream>>>(Wxz, Wcat + 1024 * 1024, 262144);
  k_f2b4<<<dim3(1024), 256, 0, stream>>>(Whh, Wrec, 262144);
  k_f2b4<<<dim3(1024), 256, 0, stream>>>(Wy, Wyb, 262144);
  k_transpose_bf16<<<dim3(32, 32), dim3(32, 8), 0, stream>>>(Whz, WhzT);

  // Mz = Wxz @ Whz  -> Wrec rows 1024..2047
  gemm_bt<1><<<dim3(8, 8), 256, 0, stream>>>(Wcat + 1024 * 1024, WhzT, nullptr, nullptr,
                                             Wrec + (size_t)1024 * 1024, 1024);
  // xhz = x @ [Wxh;Wxz]^T + [bh;bz], time-major
  gemm_bt<0><<<dim3(16, 256), 256, 0, stream>>>(xb, Wcat, bh, bz, xhz, 1024);

  // cooperative launch; 68 KB dynamic LDS (opt-in, idempotent, capture-safe)
  hipFuncSetAttribute((const void*)scan_out_k,
                      hipFuncAttributeMaxDynamicSharedMemorySize, SCAN_LDS_BYTES);
  const unsigned short* xhz_c = xhz;
  const unsigned short* Wrec_c = Wrec;
  const unsigned short* Wyb_c = Wyb;
  const float* by_c = by;
  void* kargs[] = {(void*)&xhz_c, (void*)&Wrec_c, (void*)&Wyb_c, (void*)&by_c,
                   (void*)&hb0, (void*)&hb1, (void*)&flags, (void*)&out};
  hipLaunchCooperativeKernel((void*)scan_out_k, dim3(SCAN_BLOCKS), dim3(512),
                             kargs, SCAN_LDS_BYTES, stream);
}

// Round 5
// 3426.928 us; speedup vs baseline: 1.5952x; 1.5952x over previous
//
#include <hip/hip_runtime.h>

// Problem constants (fixed by the reference): B=64, T=512, D=1024, R=1024, O=1024
#define BB 64
#define TT 512
#define DD 1024
#define RR 1024

#define SCAN_BLOCKS 64            // block g owns h-cols [16g, 16g+16)
#define HS_STRIDE 1032            // staged h row stride in bf16 (1024 + 8 pad)
#define SCAN_LDS_BYTES (64 * HS_STRIDE * 2)   // 132096; red overlay needs 36864
#define RED_STRIDE 36             // f32 elems: 32 cols + 4 pad

typedef __bf16 bf16x8 __attribute__((ext_vector_type(8)));
typedef float f32x4 __attribute__((ext_vector_type(4)));
typedef unsigned short us4 __attribute__((ext_vector_type(4)));
typedef unsigned int u32x4 __attribute__((ext_vector_type(4)));

__device__ inline unsigned short f2bf(float f) {
  unsigned int u = __float_as_uint(f);
  u = (u + 0x7fffu + ((u >> 16) & 1u)) >> 16;   // RNE
  return (unsigned short)u;
}
__device__ inline float bf2f(unsigned short b) {
  return __uint_as_float(((unsigned int)b) << 16);
}

// Coherent 16B load: bypasses L1/L2 (sc0 sc1), served by the coherence point.
// Caller must s_waitcnt vmcnt(0) (via asm) before using the result.
// Validated rule: issue in BULK (all lanes, all chunks) -> one RT total.
__device__ inline u32x4 ld16_sc(const void* p) {
  u32x4 r;
  asm volatile("global_load_dwordx4 %0, %1, off sc0 sc1"
               : "=v"(r) : "v"(p) : "memory");
  return r;
}

// ---- fp32 -> bf16 vectorized convert (n4 = n/4 groups) ----
__global__ void k_f2b4(const float* __restrict__ in, unsigned short* __restrict__ out, int n4) {
  int i = blockIdx.x * blockDim.x + threadIdx.x;
  if (i < n4) {
    const float4 v = ((const float4*)in)[i];
    us4 o;
    o.x = f2bf(v.x); o.y = f2bf(v.y); o.z = f2bf(v.z); o.w = f2bf(v.w);
    ((us4*)out)[i] = o;
  }
}

// ---- transpose 1024x1024 fp32 -> bf16 (out[j][k] = in[k][j]) ----
__global__ __launch_bounds__(256) void k_transpose_bf16(
    const float* __restrict__ in, unsigned short* __restrict__ out) {
  __shared__ float tile[32][33];
  const int bx = blockIdx.x * 32, by0 = blockIdx.y * 32;
  const int tx = threadIdx.x, ty = threadIdx.y;  // block (32,8)
#pragma unroll
  for (int r = 0; r < 32; r += 8)
    tile[ty + r][tx] = in[(size_t)(by0 + ty + r) * 1024 + bx + tx];
  __syncthreads();
#pragma unroll
  for (int r = 0; r < 32; r += 8)
    out[(size_t)(bx + ty + r) * 1024 + by0 + tx] = f2bf(tile[tx][ty + r]);
}

// ---- async global->LDS, 16B per lane ----
__device__ inline void gload_lds16(const unsigned short* g, unsigned short* l) {
  __builtin_amdgcn_global_load_lds(
      (const __attribute__((address_space(1))) unsigned int*)g,
      (__attribute__((address_space(3))) unsigned int*)l, 16, 0, 0);
}

// ---- bf16 GEMM, C[m,n] = sum_k A[m,k]*B[n,k], 128x128 tile, BK=32 ----
// EPI==0: out = xhz time-major [T][B][2048] bf16, bias folded (bh n<1024, bz else)
// EPI==1: out[m*1024+n] bf16 (Mz into Wrec rows 1024..2047)
template <int EPI>
__global__ __launch_bounds__(256) void gemm_bt(
    const unsigned short* __restrict__ A,
    const unsigned short* __restrict__ Bm,
    const float* __restrict__ bias_h,
    const float* __restrict__ bias_z,
    unsigned short* __restrict__ outb, int K) {
  __shared__ __attribute__((aligned(16))) unsigned short As[128 * 32];
  __shared__ __attribute__((aligned(16))) unsigned short Bs[128 * 32];
  const int tid = threadIdx.x;
  const int m0 = blockIdx.y * 128, n0 = blockIdx.x * 128;
  const int lane = tid & 63, wid = tid >> 6;
  const int l16 = lane & 15, quad = lane >> 4;
  const int wm = (wid & 1) * 64, wn = (wid >> 1) * 64;

  f32x4 acc[4][4] = {};

  const int c0 = tid, c1 = 256 + tid;
  const int rowA0 = c0 >> 2, colA0 = (c0 & 3) << 3;
  const int rowA1 = c1 >> 2, colA1 = (c1 & 3) << 3;

  for (int kk = 0; kk < K; kk += 32) {
    __syncthreads();
    gload_lds16(A + (size_t)(m0 + rowA0) * K + kk + colA0, As + c0 * 8);
    gload_lds16(A + (size_t)(m0 + rowA1) * K + kk + colA1, As + c1 * 8);
    gload_lds16(Bm + (size_t)(n0 + rowA0) * K + kk + colA0, Bs + c0 * 8);
    gload_lds16(Bm + (size_t)(n0 + rowA1) * K + kk + colA1, Bs + c1 * 8);
    __syncthreads();
    bf16x8 af[4], bfr[4];
#pragma unroll
    for (int i = 0; i < 4; ++i) {
      af[i] = *(const bf16x8*)&As[(wm + i * 16 + l16) * 32 + quad * 8];
      bfr[i] = *(const bf16x8*)&Bs[(wn + i * 16 + l16) * 32 + quad * 8];
    }
#pragma unroll
    for (int i = 0; i < 4; ++i)
#pragma unroll
      for (int j = 0; j < 4; ++j)
        acc[i][j] = __builtin_amdgcn_mfma_f32_16x16x32_bf16(af[i], bfr[j], acc[i][j], 0, 0, 0);
  }

#pragma unroll
  for (int i = 0; i < 4; ++i) {
#pragma unroll
    for (int j = 0; j < 4; ++j) {
#pragma unroll
      for (int r = 0; r < 4; ++r) {
        const int m = m0 + wm + i * 16 + quad * 4 + r;
        const int n = n0 + wn + j * 16 + l16;
        float v = acc[i][j][r];
        if (EPI == 0) {
          v += (n < 1024) ? bias_h[n] : bias_z[n - 1024];
          const int b = m >> 9;          // m = b*T + t, T=512
          const int t = m & 511;
          outb[((size_t)(t * 64 + b) << 11) + n] = f2bf(v);
        } else {
          outb[(size_t)m * 1024 + n] = f2bf(v);
        }
      }
    }
  }
}

// ---- persistent scan over T=512 steps + output GEMM ----
// Round-0 validated structure, re-tiled to 64 blocks x 1024 threads.
// Block g owns h-cols [16g, 16g+16); its 32 MFMA n-cols = 16 Whh rows +
// 16 Mz rows (B-frags register-resident, 8/wave). 16 waves = ks(4) x msub(2)
// x nsub(2): wave computes 2 m-tiles (32 of 64 b-rows) x 1 n-tile x K=256.
// Per step: bulk-stage full h (128 KB) global->LDS via sc0/sc1 16B loads
// (single RT), MFMA from LDS (A-read redundancy 2x, 128 KB/step vs round-0's
// 512 KB), K-reduce through a 36 KB LDS overlay, elementwise update with fp32
// register-resident master h (1 elem/thread), publish bf16 h' via relaxed
// AGENT atomics, fence-free flag barrier (round-0-validated, verbatim).
__global__ __launch_bounds__(1024) void scan_out_k(
    const unsigned short* __restrict__ xhz,   // [T][B][2048] bf16
    const unsigned short* __restrict__ Wrec,  // [2048][1024] bf16 (Whh ; Mz)
    const unsigned short* __restrict__ Wyb,   // [1024][1024] bf16
    const float* __restrict__ by,
    unsigned short* __restrict__ hb0, unsigned short* __restrict__ hb1,
    unsigned int* __restrict__ flags,
    float* __restrict__ out) {
  extern __shared__ char smem[];
  unsigned short* hs = (unsigned short*)smem;   // staged h [64][HS_STRIDE]
  float* red = (float*)smem;                    // overlay: [4][64][RED_STRIDE] f32

  const int tid = threadIdx.x, g = blockIdx.x;
  const int lane = tid & 63, wid = tid >> 6;
  const int l16 = lane & 15, quad = lane >> 4;
  const int ks = wid >> 2, msub = (wid >> 1) & 1, nsub = wid & 1;
  const int kw = ks * 256;                      // wave's K slice (bf16 elems)
  const int i0h = g * 16;                       // owned h-col base

  // loop-invariant B fragments: 16 n-cols x 256 k slice -> 32 VGPRs
  const int bcol = (nsub == 0) ? (i0h + l16) : (1024 + i0h + l16);
  const unsigned short* Bb = Wrec + (size_t)bcol * 1024 + kw + quad * 8;
  bf16x8 bfr[8];
#pragma unroll
  for (int s = 0; s < 8; ++s) bfr[s] = *(const bf16x8*)(Bb + s * 32);

  // staging coords: thread copies 8 x 16B chunks of row sr (stride 256B)
  const int sr = tid >> 4;          // h row (b) 0..63
  const int su = tid & 15;          // 16B unit within row
  const unsigned short* gsrc_base0 = hb0 + sr * 1024 + su * 8;
  const unsigned short* gsrc_base1 = hb1 + sr * 1024 + su * 8;
  unsigned short* ldst = hs + sr * HS_STRIDE + su * 8;

  // elementwise coords: thread owns (b=eb, col i0h+ec)
  const int eb = tid >> 4, ec = tid & 15;
  float hold = 0.0f;                // fp32 master h, register-resident

  const unsigned short* gsrc = gsrc_base0;

  for (int tt = 0; tt < TT; ++tt) {
    unsigned short* hbn = (tt & 1) ? hb0 : hb1;

    // ---- stage h -> LDS (bulk 16B coherent loads, one RT) + xhz prefetch ----
    u32x4 tmp[8];
#pragma unroll
    for (int c = 0; c < 8; ++c)
      tmp[c] = ld16_sc((const char*)gsrc + c * 256);
    const size_t xrow = ((size_t)(tt * 64 + eb)) << 11;
    const unsigned short xh = xhz[xrow + i0h + ec];
    const unsigned short xz = xhz[xrow + 1024 + i0h + ec];
    asm volatile("s_waitcnt vmcnt(0)" ::: "memory");
#pragma unroll
    for (int c = 0; c < 8; ++c)
      *(u32x4*)(ldst + c * 128) = tmp[c];       // c*256 bytes
    __syncthreads();

    // ---- MFMA: acc[mt] over this wave's 32 b-rows, 1 n-tile, K=256 ----
    f32x4 acc[2] = {};
#pragma unroll
    for (int s = 0; s < 8; ++s) {
#pragma unroll
      for (int mt = 0; mt < 2; ++mt) {
        const bf16x8 afr = *(const bf16x8*)(
            hs + (msub * 32 + mt * 16 + l16) * HS_STRIDE + kw + s * 32 + quad * 8);
        acc[mt] = __builtin_amdgcn_mfma_f32_16x16x32_bf16(afr, bfr[s], acc[mt], 0, 0, 0);
      }
    }
    __syncthreads();   // all ds_reads of hs done; safe to overlay red

    // ---- K-reduction partials into LDS ----
#pragma unroll
    for (int mt = 0; mt < 2; ++mt)
#pragma unroll
      for (int r = 0; r < 4; ++r)
        red[(size_t)(ks * 64 + msub * 32 + mt * 16 + quad * 4 + r) * RED_STRIDE +
            nsub * 16 + l16] = acc[mt][r];
    __syncthreads();

    // ---- elementwise update (1024 threads x 1 elem) ----
    float ph = 0.f, pz = 0.f;
#pragma unroll
    for (int w = 0; w < 4; ++w) {
      const float* rb = red + (size_t)(w * 64 + eb) * RED_STRIDE;
      ph += rb[ec];
      pz += rb[16 + ec];
    }
    {
      const float z = 1.0f / (1.0f + __expf(-(bf2f(xz) + pz)));
      const float hbv = fmaxf(bf2f(xh) + ph, 0.0f);
      hold = z * hold + (1.0f - z) * hbv;
      __hip_atomic_store(hbn + (size_t)eb * 1024 + i0h + ec, f2bf(hold),
                         __ATOMIC_RELAXED, __HIP_MEMORY_SCOPE_AGENT);
    }

    // ---- fence-free grid barrier (round-0 validated, verbatim) ----
    __syncthreads();   // drains each wave's vmcnt -> all h' stores visible
    if (tid == 0)
      __hip_atomic_store(&flags[g], (unsigned int)(tt + 1),
                         __ATOMIC_RELAXED, __HIP_MEMORY_SCOPE_AGENT);
    if (tid < 64) {
      const unsigned int tgt = (unsigned int)(tt + 1);
      unsigned int v;
      do {
        v = __hip_atomic_load(&flags[tid & 63], __ATOMIC_RELAXED, __HIP_MEMORY_SCOPE_AGENT);
      } while (__any(v < tgt));
    }
    __syncthreads();

    gsrc = (tt & 1) ? gsrc_base0 : gsrc_base1;   // next source = buffer just written
  }

  // ---- epilogue: out = h_final @ Wy^T + by ----
  // h_final in hb0 (tt=511 wrote hb0). Stage it, then nsub==0 waves (8)
  // compute the block's 16 out-cols; reduce through red; all threads store.
  {
    u32x4 tmp[8];
#pragma unroll
    for (int c = 0; c < 8; ++c)
      tmp[c] = ld16_sc((const char*)(hb0 + sr * 1024 + su * 8) + c * 256);
    asm volatile("s_waitcnt vmcnt(0)" ::: "memory");
#pragma unroll
    for (int c = 0; c < 8; ++c)
      *(u32x4*)(ldst + c * 128) = tmp[c];
  }
  __syncthreads();

  f32x4 oacc[2] = {};
  if (nsub == 0) {   // 8 waves (ks x msub) cover 16 out-cols x 64 rows x K
    const int ocol = i0h + l16;
    const unsigned short* Byb = Wyb + (size_t)ocol * 1024 + kw + quad * 8;
#pragma unroll
    for (int s = 0; s < 8; ++s) {
      const bf16x8 byf = *(const bf16x8*)(Byb + s * 32);
#pragma unroll
      for (int mt = 0; mt < 2; ++mt) {
        const bf16x8 afr = *(const bf16x8*)(
            hs + (msub * 32 + mt * 16 + l16) * HS_STRIDE + kw + s * 32 + quad * 8);
        oacc[mt] = __builtin_amdgcn_mfma_f32_16x16x32_bf16(afr, byf, oacc[mt], 0, 0, 0);
      }
    }
  }
  __syncthreads();   // all hs reads done before red overlay writes
  if (nsub == 0) {
#pragma unroll
    for (int mt = 0; mt < 2; ++mt)
#pragma unroll
      for (int r = 0; r < 4; ++r)
        red[(size_t)(ks * 64 + msub * 32 + mt * 16 + quad * 4 + r) * RED_STRIDE +
            l16] = oacc[mt][r];
  }
  __syncthreads();

  {
    float o = by[i0h + ec];
#pragma unroll
    for (int w = 0; w < 4; ++w)
      o += red[(size_t)(w * 64 + eb) * RED_STRIDE + ec];
    out[(size_t)eb * 1024 + i0h + ec] = o;
  }
}

extern "C" void kernel_launch(void* const* d_in, const int* in_sizes, int n_in,
                              void* d_out, int out_size, void* d_ws, size_t ws_size,
                              hipStream_t stream) {
  const float* x = (const float*)d_in[0];
  const float* Wxh = (const float*)d_in[1];
  const float* bh = (const float*)d_in[2];
  const float* Whh = (const float*)d_in[3];
  const float* Wxz = (const float*)d_in[4];
  const float* bz = (const float*)d_in[5];
  const float* Whz = (const float*)d_in[6];
  const float* Wy = (const float*)d_in[7];
  const float* by = (const float*)d_in[8];
  float* out = (float*)d_out;

  char* ws = (char*)d_ws;
  size_t off = 0;
  auto alloc = [&](size_t bytes) -> void* {
    void* p = ws + off;
    off += (bytes + 255) & ~(size_t)255;
    return p;
  };
  const size_t nX = (size_t)BB * TT * DD;  // 33554432
  unsigned short* xb = (unsigned short*)alloc(nX * 2);                  // x bf16
  unsigned short* Wcat = (unsigned short*)alloc((size_t)2048 * 1024 * 2);  // [Wxh;Wxz]
  unsigned short* WhzT = (unsigned short*)alloc((size_t)1024 * 1024 * 2);  // Whz^T
  unsigned short* Wrec = (unsigned short*)alloc((size_t)2048 * 1024 * 2);  // [Whh;Mz]
  unsigned short* Wyb = (unsigned short*)alloc((size_t)1024 * 1024 * 2);   // Wy bf16
  unsigned short* xhz = (unsigned short*)alloc((size_t)TT * BB * 2048 * 2);  // 128 MB
  unsigned short* hb0 = (unsigned short*)alloc((size_t)BB * RR * 2);
  unsigned short* hb1 = (unsigned short*)alloc((size_t)BB * RR * 2);
  unsigned int* flags = (unsigned int*)alloc(1024);

  hipMemsetAsync(hb0, 0, (size_t)BB * RR * 2, stream);
  hipMemsetAsync(flags, 0, 1024, stream);

  // weight / input conversions
  k_f2b4<<<dim3((unsigned)(nX / 4 / 256)), 256, 0, stream>>>(x, xb, (int)(nX / 4));
  k_f2b4<<<dim3(1024), 256, 0, stream>>>(Wxh, Wcat, 262144);
  k_f2b4<<<dim3(1024), 256, 0, stream>>>(Wxz, Wcat + 1024 * 1024, 262144);
  k_f2b4<<<dim3(1024), 256, 0, stream>>>(Whh, Wrec, 262144);
  k_f2b4<<<dim3(1024), 256, 0, stream>>>(Wy, Wyb, 262144);
  k_transpose_bf16<<<dim3(32, 32), dim3(32, 8), 0, stream>>>(Whz, WhzT);

  // Mz = Wxz @ Whz  -> Wrec rows 1024..2047
  gemm_bt<1><<<dim3(8, 8), 256, 0, stream>>>(Wcat + 1024 * 1024, WhzT, nullptr, nullptr,
                                             Wrec + (size_t)1024 * 1024, 1024);
  // xhz = x @ [Wxh;Wxz]^T + [bh;bz], time-major
  gemm_bt<0><<<dim3(16, 256), 256, 0, stream>>>(xb, Wcat, bh, bz, xhz, 1024);

  // cooperative launch; opt in to 129 KB dynamic LDS (idempotent, capture-safe)
  hipFuncSetAttribute((const void*)scan_out_k,
                      hipFuncAttributeMaxDynamicSharedMemorySize, SCAN_LDS_BYTES);
  const unsigned short* xhz_c = xhz;
  const unsigned short* Wrec_c = Wrec;
  const unsigned short* Wyb_c = Wyb;
  const float* by_c = by;
  void* kargs[] = {(void*)&xhz_c, (void*)&Wrec_c, (void*)&Wyb_c, (void*)&by_c,
                   (void*)&hb0, (void*)&hb1, (void*)&flags, (void*)&out};
  hipLaunchCooperativeKernel((void*)scan_out_k, dim3(SCAN_BLOCKS), dim3(1024),
                             kargs, SCAN_LDS_BYTES, stream);
}